// Round 7
// baseline (299.016 us; speedup 1.0000x reference)
//
#include <hip/hip_runtime.h>
#include <hip/hip_cooperative_groups.h>

namespace cg = cooperative_groups;

#define GX 192
#define GY 96
#define GZ 192
#define GRP (GY*GZ)            // 18432 (y,z) groups
#define NVOX (GX*GRP)          // 3538944 voxels
#define NXC 12                 // x-chunks
#define XCW (GX/NXC)           // 16 voxels per unit
#define CSTR 16                // bytes per group in u8 count buffer (12 used)
#define UNITS (NXC*GRP)        // 221184 prep units

// workspace byte offsets
#define WS_MVP    0                        // 16 floats (fallback path only)
#define WS_DEPTH  64                       // GRP u32 depth bits
#define WS_CNT8   (WS_DEPTH + GRP*4)       // GRP x CSTR u8 partial counts
#define WS_SEL    (WS_CNT8 + GRP*CSTR)     // 2 u32: T, R
#define WS_TLIST  (WS_SEL + 16)            // 256 u32 tied group ids (sorted)
#define WS_TPREF  (WS_TLIST + 1024)        // GX u32 excl prefix of tied-valid per x
#define WS_NTIED  (WS_TPREF + GX*4)        // 1 u32

typedef float f4 __attribute__((ext_vector_type(4)));

#define BSUM(w) (((w) & 255u) + (((w) >> 8) & 255u) + (((w) >> 16) & 255u) + ((w) >> 24))

// Replicate reference fp32 arithmetic exactly:
//   clip_c = fma(cz, M[c][2], fma(cy, M[c][1], cx*M[c][0])) + M[c][3]
__device__ __forceinline__ bool voxel_valid(int x, int g,
                                            const float* __restrict__ occL,
                                            const float* M,
                                            float* occ_out)
{
    int y = g / GZ;
    int z = g - y * GZ;
    float cx = (float)(2 * x - 191);
    float cy = (float)(2 * y + 1);
    float cz = (float)(2 * z - 191);

    float logit = occL[(size_t)x * GRP + g];
    float occ = 1.0f / (1.0f + expf(-logit));
    *occ_out = occ;
    if (!(occ > 0.01f)) return false;

    float c0 = __fadd_rn(__fmaf_rn(cz, M[2],  __fmaf_rn(cy, M[1],  __fmul_rn(cx, M[0]))),  M[3]);
    float c1 = __fadd_rn(__fmaf_rn(cz, M[6],  __fmaf_rn(cy, M[5],  __fmul_rn(cx, M[4]))),  M[7]);
    float c2 = __fadd_rn(__fmaf_rn(cz, M[10], __fmaf_rn(cy, M[9],  __fmul_rn(cx, M[8]))),  M[11]);
    float c3 = __fadd_rn(__fmaf_rn(cz, M[14], __fmaf_rn(cy, M[13], __fmul_rn(cx, M[12]))), M[15]);

    float w  = fmaxf(c3, 1e-6f);
    float nx = c0 / w;
    float ny = c1 / w;
    float nz = c2 / w;
    return (nx >= -1.0f) && (nx <= 1.0f) &&
           (ny >= -1.0f) && (ny <= 1.0f) &&
           (nz >= -1.0f) && (nz <= 1.0f);
}

__device__ __forceinline__ void compute_mvp_lds(const float* view, const float* proj,
                                                float* s_mvp, int tid)
{
    if (tid < 16) {
        int r = tid >> 2, c = tid & 3;
        float acc = 0.0f;
        for (int k = 0; k < 4; ++k)
            acc = __fadd_rn(acc, __fmul_rn(proj[r * 4 + k], view[k * 4 + c]));
        s_mvp[tid] = acc;
    }
}

__device__ __forceinline__ unsigned depth_bits(int g, const float* view)
{
    int y = g / GZ;
    int z = g - y * GZ;
    float cy = (float)(2 * y + 1);
    float cz = (float)(2 * z - 191);
    float seed = __fmul_rn(-191.0f, view[8]);
    float vz = __fadd_rn(__fmaf_rn(cz, view[10], __fmaf_rn(cy, view[9], seed)), view[11]);
    return __float_as_uint(fmaxf(-vz, 0.0f));   // d >= 0: bits order-monotone
}

__device__ __forceinline__ unsigned wave_incl_scan(unsigned v, int lane)
{
    #pragma unroll
    for (int off = 1; off < 64; off <<= 1) {
        unsigned u = (unsigned)__shfl_up((int)v, off);
        if (lane >= off) v += u;
    }
    return v;
}

// one prep unit: depth (idx<GRP) + u8 valid count for 16 x's of one group
__device__ __forceinline__ void prep_unit(int idx,
    const float* __restrict__ occL, const float* M, const float* view,
    unsigned* __restrict__ depthB, unsigned char* __restrict__ cnt8)
{
    int xc = idx / GRP;
    int g  = idx - xc * GRP;
    if (idx < GRP) depthB[g] = depth_bits(g, view);
    unsigned c = 0;
    int x0 = xc * XCW;
    for (int j = 0; j < XCW; ++j) {
        float occ;
        if (voxel_valid(x0 + j, g, occL, M, &occ)) ++c;
    }
    cnt8[(size_t)g * CSTR + xc] = (unsigned char)c;
}

// full weighted selection with 256 threads, streaming (depth,cnt) from global
// (L2-resident). Integer-identical to the verified radix walk.
__device__ void select_256(const unsigned* __restrict__ depthB,
                           const unsigned char* __restrict__ cnt8,
                           unsigned K,
                           const float* __restrict__ occL,
                           const float* s_mvp,
                           unsigned* __restrict__ sel,
                           unsigned* __restrict__ tiedList,
                           unsigned* __restrict__ tiedPrefX,
                           unsigned* __restrict__ nTiedG,
                           int tid)
{
    __shared__ unsigned s_h[4096];
    __shared__ unsigned s_w[4];
    __shared__ unsigned s_wT[4], s_wMn[4], s_wMx[4];
    __shared__ unsigned s_tot, s_mn, s_mx, s_chTot;
    __shared__ unsigned s_found, s_prefix, s_remK;
    __shared__ unsigned s_list[256];
    __shared__ int s_n;
    __shared__ unsigned s_cntX[GX];

    int lane = tid & 63;
    int wid  = tid >> 6;

    // sweep 1: total valid + min/max of top-16 depth bits (weighted)
    unsigned tot = 0, mn = 0xFFFFFFFFu, mx = 0;
    for (int g = tid; g < GRP; g += 256) {
        const uint4 cw = *(const uint4*)(cnt8 + (size_t)g * CSTR);
        unsigned cc = BSUM(cw.x) + BSUM(cw.y) + BSUM(cw.z);
        if (cc) {
            unsigned hi = depthB[g] >> 16;
            mn = min(mn, hi);
            mx = max(mx, hi);
            tot += cc;
        }
    }
    for (int m = 1; m < 64; m <<= 1) {
        tot += (unsigned)__shfl_xor((int)tot, m);
        mn = min(mn, (unsigned)__shfl_xor((int)mn, m));
        mx = max(mx, (unsigned)__shfl_xor((int)mx, m));
    }
    if (lane == 0) { s_wT[wid] = tot; s_wMn[wid] = mn; s_wMx[wid] = mx; }
    __syncthreads();
    if (tid == 0) {
        unsigned t2 = 0, m2 = 0xFFFFFFFFu, x2 = 0;
        for (int w = 0; w < 4; ++w) {
            t2 += s_wT[w]; m2 = min(m2, s_wMn[w]); x2 = max(x2, s_wMx[w]);
        }
        s_tot = t2; s_mn = m2; s_mx = x2;
        s_found = 0;
    }
    __syncthreads();
    tot = s_tot; mn = s_mn; mx = s_mx;

    if (tot <= K) {                          // keep all valid
        if (tid == 0) {
            sel[0] = 0xFFFFFFFFu;
            sel[1] = 0x7FFFFFFFu;
            *nTiedG = 0u;
        }
        return;                              // uniform exit
    }

    // pass A: 16-bit windowed histogram, chunks of 4096 bins
    unsigned remK = K;
    unsigned prefix = 0;
    unsigned span = mx - mn + 1u;
    unsigned nchunks = (span + 4095u) / 4096u;
    for (unsigned ch = 0; ch < nchunks; ++ch) {
        unsigned base = mn + ch * 4096u;
        for (int j = tid; j < 4096; j += 256) s_h[j] = 0;
        __syncthreads();
        for (int g = tid; g < GRP; g += 256) {
            const uint4 cw = *(const uint4*)(cnt8 + (size_t)g * CSTR);
            unsigned cc = BSUM(cw.x) + BSUM(cw.y) + BSUM(cw.z);
            if (!cc) continue;
            unsigned hi = depthB[g] >> 16;
            if (hi >= base && hi < base + 4096u)
                atomicAdd(&s_h[hi - base], cc);
        }
        __syncthreads();
        unsigned ps = 0;
        #pragma unroll
        for (int j = 0; j < 16; ++j) ps += s_h[tid * 16 + j];
        unsigned iw = wave_incl_scan(ps, lane);
        if (lane == 63) s_w[wid] = iw;
        __syncthreads();
        if (wid == 0) {
            unsigned wv = (lane < 4) ? s_w[lane] : 0u;
            unsigned wiw = wave_incl_scan(wv, lane);
            if (lane < 4) s_w[lane] = wiw - wv;   // exclusive wave offset
            if (lane == 3) s_chTot = wiw;         // chunk total
        }
        __syncthreads();
        unsigned incl = iw + s_w[wid];
        unsigned chunkTot = s_chTot;
        unsigned excl = incl - ps;
        if (remK <= chunkTot && excl < remK && remK <= incl) {
            unsigned cum = excl;
            #pragma unroll
            for (int j = 0; j < 16; ++j) {
                unsigned hv = s_h[tid * 16 + j];
                if (cum < remK && remK <= cum + hv) {
                    s_found  = 1u;
                    s_prefix = base + (unsigned)(tid * 16 + j);
                    s_remK   = remK - cum;
                }
                cum += hv;
            }
        }
        __syncthreads();
        if (s_found) { prefix = s_prefix; remK = s_remK; break; }
        remK -= chunkTot;                    // uniform
        __syncthreads();
    }

    // passes B, C: 8-bit refine (bits 15..8 then 7..0)
    for (int p = 0; p < 2; ++p) {
        int matchShift = (p == 0) ? 16 : 8;
        int digitShift = (p == 0) ? 8 : 0;
        s_h[tid] = 0;
        __syncthreads();
        for (int g = tid; g < GRP; g += 256) {
            const uint4 cw = *(const uint4*)(cnt8 + (size_t)g * CSTR);
            unsigned cc = BSUM(cw.x) + BSUM(cw.y) + BSUM(cw.z);
            if (!cc) continue;
            unsigned db = depthB[g];
            if ((db >> matchShift) == prefix)
                atomicAdd(&s_h[(db >> digitShift) & 255u], cc);
        }
        __syncthreads();
        unsigned ps = s_h[tid];
        unsigned iw = wave_incl_scan(ps, lane);
        if (lane == 63) s_w[wid] = iw;
        __syncthreads();
        if (wid == 0) {
            unsigned wv = (lane < 4) ? s_w[lane] : 0u;
            unsigned wiw = wave_incl_scan(wv, lane);
            if (lane < 4) s_w[lane] = wiw - wv;
        }
        __syncthreads();
        unsigned incl = iw + s_w[wid];
        unsigned excl = incl - ps;
        if (excl < remK && remK <= incl) {   // unique crossing thread
            s_prefix = (prefix << 8) | (unsigned)tid;
            s_remK   = remK - excl;
        }
        __syncthreads();
        prefix = s_prefix; remK = s_remK;
        __syncthreads();
    }
    unsigned T = prefix;                     // final threshold depth bits
    unsigned R = remK;                       // quota at exactly T

    // tied groups: sorted list + per-x valid prefix (recompute from occL)
    if (tid == 0) s_n = 0;
    if (tid < GX) s_cntX[tid] = 0;
    __syncthreads();
    for (int g = tid; g < GRP; g += 256) {
        if (depthB[g] == T) {
            int idx = atomicAdd(&s_n, 1);
            if (idx < 256) s_list[idx] = (unsigned)g;
        }
    }
    __syncthreads();
    int n = min(s_n, 256);
    if (tid == 0) {
        for (int a = 1; a < n; ++a) {        // insertion sort (n tiny)
            unsigned v = s_list[a];
            int b = a - 1;
            while (b >= 0 && s_list[b] > v) { s_list[b + 1] = s_list[b]; --b; }
            s_list[b + 1] = v;
        }
    }
    __syncthreads();
    int pairs = GX * n;
    for (int pr = tid; pr < pairs; pr += 256) {
        int x = pr / n;
        int s = pr - x * n;
        float occ;
        if (voxel_valid(x, (int)s_list[s], occL, s_mvp, &occ))
            atomicAdd(&s_cntX[x], 1u);
    }
    __syncthreads();
    if (tid == 0) {
        unsigned run = 0;
        for (int x = 0; x < GX; ++x) { tiedPrefX[x] = run; run += s_cntX[x]; }
        *nTiedG = (unsigned)n;
        sel[0] = T;
        sel[1] = R;
    }
    if (tid < n) tiedList[tid] = s_list[tid];
}

// one output voxel (R5-verified body: recompute predicate from occL)
__device__ __forceinline__ void out_one(int i,
    const float* __restrict__ occL, const float* __restrict__ matL,
    const float* M, const unsigned* __restrict__ depthB,
    unsigned T, unsigned R,
    const unsigned* __restrict__ tiedList, const unsigned* __restrict__ tiedPrefX,
    unsigned nT, float* __restrict__ out)
{
    int x = i / GRP;
    int g = i - x * GRP;

    float occ;
    bool valid = voxel_valid(x, g, occL, M, &occ);
    bool keep = false;
    if (valid) {
        unsigned db = depthB[g];
        if (db < T) {
            keep = true;
        } else if (db == T) {
            unsigned rank = tiedPrefX[x];
            for (unsigned s = 0; s < nT; ++s) {
                unsigned gs = tiedList[s];
                if (gs >= (unsigned)g) break;
                float o2;
                if (voxel_valid(x, (int)gs, occL, M, &o2)) ++rank;
            }
            keep = rank < R;
        }
    }

    f4 o0 = (f4)(0.0f);
    f4 o1 = (f4)(0.0f);
    if (keep) {
        const f4* mp = reinterpret_cast<const f4*>(matL) + (size_t)i * 2;
        f4 a = __builtin_nontemporal_load(mp);
        f4 b = __builtin_nontemporal_load(mp + 1);
        float mx = fmaxf(fmaxf(fmaxf(a[0], a[1]), fmaxf(a[2], a[3])),
                         fmaxf(fmaxf(b[0], b[1]), fmaxf(b[2], b[3])));
        float e0 = expf(a[0] - mx), e1 = expf(a[1] - mx), e2 = expf(a[2] - mx), e3 = expf(a[3] - mx);
        float e4 = expf(b[0] - mx), e5 = expf(b[1] - mx), e6 = expf(b[2] - mx), e7 = expf(b[3] - mx);
        float s = ((e0 + e1) + (e2 + e3)) + ((e4 + e5) + (e6 + e7));
        float inv = occ / s;
        o0[0] = e0 * inv; o0[1] = e1 * inv; o0[2] = e2 * inv; o0[3] = e3 * inv;
        o1[0] = e4 * inv; o1[1] = e5 * inv; o1[2] = e6 * inv; o1[3] = e7 * inv;
    }
    f4* op = reinterpret_cast<f4*>(out) + (size_t)i * 2;
    __builtin_nontemporal_store(o0, op);
    __builtin_nontemporal_store(o1, op + 1);
}

// ---------------- cooperative fused kernel (1 node) ----------------
__global__ __launch_bounds__(256, 4) void k_fused(
    const float* __restrict__ occL, const float* __restrict__ matL,
    const float* __restrict__ view, const float* __restrict__ proj,
    const int* __restrict__ mb, float* __restrict__ out,
    unsigned* __restrict__ depthB, unsigned char* __restrict__ cnt8,
    unsigned* __restrict__ sel, unsigned* __restrict__ tiedList,
    unsigned* __restrict__ tiedPref, unsigned* __restrict__ nTied)
{
    cg::grid_group grid = cg::this_grid();
    __shared__ float s_mvp[16];
    int tid = threadIdx.x;
    compute_mvp_lds(view, proj, s_mvp, tid);
    __syncthreads();

    int nthreads = (int)gridDim.x * 256;
    int gtid = (int)blockIdx.x * 256 + tid;

    // P1: prep (depth + u8 counts)
    for (int idx = gtid; idx < UNITS; idx += nthreads)
        prep_unit(idx, occL, s_mvp, view, depthB, cnt8);

    grid.sync();

    // P2: selection on block 0 only
    if (blockIdx.x == 0)
        select_256(depthB, cnt8, (unsigned)mb[0], occL, s_mvp,
                   sel, tiedList, tiedPref, nTied, tid);

    grid.sync();

    // P3: output (grid-stride)
    unsigned T = sel[0];
    unsigned R = sel[1];
    unsigned nT = *nTied;
    for (int i = gtid; i < NVOX; i += nthreads)
        out_one(i, occL, matL, s_mvp, depthB, T, R, tiedList, tiedPref, nT, out);
}

// ---------------- fallback path (R5 3-kernel structure) ----------------
__global__ __launch_bounds__(256) void k_prep_fb(
    const float* __restrict__ view, const float* __restrict__ proj,
    const float* __restrict__ occL,
    float* __restrict__ mvpOut, unsigned* __restrict__ depthB,
    unsigned char* __restrict__ cnt8)
{
    __shared__ float s_mvp[16];
    int tid = threadIdx.x;
    compute_mvp_lds(view, proj, s_mvp, tid);
    __syncthreads();
    if (blockIdx.x == 0 && tid < 16) mvpOut[tid] = s_mvp[tid];
    int idx = blockIdx.x * 256 + tid;
    if (idx < UNITS)
        prep_unit(idx, occL, s_mvp, view, depthB, cnt8);
}

__global__ __launch_bounds__(256) void k_select_fb(
    const float* __restrict__ view, const float* __restrict__ proj,
    const float* __restrict__ occL,
    const unsigned* __restrict__ depthB, const unsigned char* __restrict__ cnt8,
    const int* __restrict__ mb,
    unsigned* __restrict__ sel, unsigned* __restrict__ tiedList,
    unsigned* __restrict__ tiedPref, unsigned* __restrict__ nTied)
{
    __shared__ float s_mvp[16];
    int tid = threadIdx.x;
    compute_mvp_lds(view, proj, s_mvp, tid);
    __syncthreads();
    select_256(depthB, cnt8, (unsigned)mb[0], occL, s_mvp,
               sel, tiedList, tiedPref, nTied, tid);
}

__global__ __launch_bounds__(256) void k_out_fb(
    const float* __restrict__ occL, const float* __restrict__ matL,
    const float* __restrict__ mvp, const unsigned* __restrict__ depthB,
    const unsigned* __restrict__ sel, const unsigned* __restrict__ tiedList,
    const unsigned* __restrict__ tiedPref, const unsigned* __restrict__ nTied,
    float* __restrict__ out)
{
    int i = blockIdx.x * 256 + threadIdx.x;
    if (i >= NVOX) return;
    out_one(i, occL, matL, mvp, depthB, sel[0], sel[1], tiedList, tiedPref, *nTied, out);
}

extern "C" void kernel_launch(void* const* d_in, const int* in_sizes, int n_in,
                              void* d_out, int out_size, void* d_ws, size_t ws_size,
                              hipStream_t stream)
{
    const float* occL = (const float*)d_in[0];
    const float* matL = (const float*)d_in[1];
    const float* view = (const float*)d_in[2];
    const float* proj = (const float*)d_in[3];
    const int*   mb   = (const int*)d_in[4];
    float* out = (float*)d_out;

    char* ws = (char*)d_ws;
    float*          mvp      = (float*)(ws + WS_MVP);
    unsigned*       depthB   = (unsigned*)(ws + WS_DEPTH);
    unsigned char*  cnt8     = (unsigned char*)(ws + WS_CNT8);
    unsigned*       sel      = (unsigned*)(ws + WS_SEL);
    unsigned*       tiedList = (unsigned*)(ws + WS_TLIST);
    unsigned*       tiedPref = (unsigned*)(ws + WS_TPREF);
    unsigned*       nTied    = (unsigned*)(ws + WS_NTIED);

    // cooperative single-node path: grid sized for guaranteed co-residency
    int occB = 0;
    hipError_t qe = hipOccupancyMaxActiveBlocksPerMultiprocessor(
        &occB, (const void*)k_fused, 256, 0);
    bool coop = (qe == hipSuccess && occB > 0);
    if (coop) {
        long long cap = (long long)occB * 256;   // 256 CUs on MI355X
        int gridB = (cap > 1024) ? 1024 : (int)cap;
        void* args[] = { (void*)&occL, (void*)&matL, (void*)&view, (void*)&proj,
                         (void*)&mb, (void*)&out, (void*)&depthB, (void*)&cnt8,
                         (void*)&sel, (void*)&tiedList, (void*)&tiedPref, (void*)&nTied };
        hipError_t le = hipLaunchCooperativeKernel((const void*)k_fused,
                                                   dim3(gridB), dim3(256),
                                                   args, 0, stream);
        if (le != hipSuccess) { (void)hipGetLastError(); coop = false; }
    }
    if (!coop) {
        k_prep_fb<<<UNITS / 256, 256, 0, stream>>>(view, proj, occL, mvp, depthB, cnt8);
        k_select_fb<<<1, 256, 0, stream>>>(view, proj, occL, depthB, cnt8, mb,
                                           sel, tiedList, tiedPref, nTied);
        k_out_fb<<<NVOX / 256, 256, 0, stream>>>(occL, matL, mvp, depthB, sel,
                                                 tiedList, tiedPref, nTied, out);
    }
}

// Round 8
// 69.390 us; speedup vs baseline: 4.3092x; 4.3092x over previous
//
#include <hip/hip_runtime.h>

#define GX 192
#define GY 96
#define GZ 192
#define GRP (GY*GZ)            // 18432 (y,z) groups
#define NVOX (GX*GRP)          // 3538944 voxels

#define NXC 12                 // x-chunks
#define XCW (GX/NXC)           // 16 voxels per thread/chunk
#define GBLK (GRP/256)         // 72 blocks per chunk
#define CSTR 16                // bytes per group in u8 count buffer (12 used, 4 pad)

#define K2T 1024               // select kernel threads
#define GPT (GRP/K2T)          // 18 groups per thread
#define WBINS 4096             // window chunk bins (16-bit pass)
#define BPT (WBINS/K2T)        // 4 bins per thread

// workspace byte offsets
#define WS_MVP    0                        // 16 floats
#define WS_DEPTH  64                       // GRP u32 depth bits
#define WS_CNT8   (WS_DEPTH + GRP*4)       // GRP x CSTR u8 partial counts
#define WS_SEL    (WS_CNT8 + GRP*CSTR)     // 2 u32: T, R
#define WS_TLIST  (WS_SEL + 16)            // 256 u32 tied group ids (sorted)
#define WS_TPREF  (WS_TLIST + 1024)        // GX u32 excl prefix of tied-valid per x
#define WS_NTIED  (WS_TPREF + GX*4)        // 1 u32

typedef float f4 __attribute__((ext_vector_type(4)));

#define BSUM(w) (((w) & 255u) + (((w) >> 8) & 255u) + (((w) >> 16) & 255u) + ((w) >> 24))

// Replicate reference fp32 arithmetic exactly:
//   clip_c = fma(cz, M[c][2], fma(cy, M[c][1], cx*M[c][0])) + M[c][3]
__device__ __forceinline__ bool voxel_valid(int x, int g,
                                            const float* __restrict__ occL,
                                            const float* M,
                                            float* occ_out)
{
    int y = g / GZ;
    int z = g - y * GZ;
    float cx = (float)(2 * x - 191);
    float cy = (float)(2 * y + 1);
    float cz = (float)(2 * z - 191);

    float logit = occL[(size_t)x * GRP + g];
    float occ = 1.0f / (1.0f + expf(-logit));
    *occ_out = occ;
    if (!(occ > 0.01f)) return false;

    float c0 = __fadd_rn(__fmaf_rn(cz, M[2],  __fmaf_rn(cy, M[1],  __fmul_rn(cx, M[0]))),  M[3]);
    float c1 = __fadd_rn(__fmaf_rn(cz, M[6],  __fmaf_rn(cy, M[5],  __fmul_rn(cx, M[4]))),  M[7]);
    float c2 = __fadd_rn(__fmaf_rn(cz, M[10], __fmaf_rn(cy, M[9],  __fmul_rn(cx, M[8]))),  M[11]);
    float c3 = __fadd_rn(__fmaf_rn(cz, M[14], __fmaf_rn(cy, M[13], __fmul_rn(cx, M[12]))), M[15]);

    float w  = fmaxf(c3, 1e-6f);
    float nx = c0 / w;
    float ny = c1 / w;
    float nz = c2 / w;
    return (nx >= -1.0f) && (nx <= 1.0f) &&
           (ny >= -1.0f) && (ny <= 1.0f) &&
           (nz >= -1.0f) && (nz <= 1.0f);
}

__device__ __forceinline__ void compute_mvp_lds(const float* view, const float* proj,
                                                float* s_mvp, int tid)
{
    if (tid < 16) {
        int r = tid >> 2, c = tid & 3;
        float acc = 0.0f;
        for (int k = 0; k < 4; ++k)
            acc = __fadd_rn(acc, __fmul_rn(proj[r * 4 + k], view[k * 4 + c]));
        s_mvp[tid] = acc;
    }
}

__device__ __forceinline__ unsigned wave_incl_scan(unsigned v, int lane)
{
    #pragma unroll
    for (int off = 1; off < 64; off <<= 1) {
        unsigned u = (unsigned)__shfl_up((int)v, off);
        if (lane >= off) v += u;
    }
    return v;
}

// K1: mvp (block 0 -> ws), depth bits (xc==0), u8 partial valid counts per x-chunk.
// grid = NXC * GBLK = 864 blocks of 256. No atomics, no pre-zeroing needed.
__global__ __launch_bounds__(256) void k_prep_count(
    const float* __restrict__ view, const float* __restrict__ proj,
    const float* __restrict__ occL,
    float* __restrict__ mvpOut,
    unsigned* __restrict__ depthBits,
    unsigned char* __restrict__ cnt8)
{
    __shared__ float s_mvp[16];
    int tid = threadIdx.x;
    compute_mvp_lds(view, proj, s_mvp, tid);
    __syncthreads();

    int b  = blockIdx.x;
    int gb = b % GBLK;
    int xc = b / GBLK;
    int g  = gb * 256 + tid;

    if (b == 0 && tid < 16) mvpOut[tid] = s_mvp[tid];

    if (xc == 0) {
        int y = g / GZ;
        int z = g - y * GZ;
        float cy = (float)(2 * y + 1);
        float cz = (float)(2 * z - 191);
        float seed = __fmul_rn(-191.0f, view[8]);
        float vz = __fadd_rn(__fmaf_rn(cz, view[10], __fmaf_rn(cy, view[9], seed)), view[11]);
        float d  = fmaxf(-vz, 0.0f);
        depthBits[g] = __float_as_uint(d);   // d >= 0: bits order-monotone
    }

    unsigned c = 0;
    int x0 = xc * XCW;
    #pragma unroll
    for (int j = 0; j < XCW; ++j) {
        float occ;
        if (voxel_valid(x0 + j, g, occL, s_mvp, &occ)) ++c;
    }
    cnt8[(size_t)g * CSTR + xc] = (unsigned char)c;
}

// K2: full weighted selection + tied-group prep in ONE block of 1024 threads.
// Integer-identical to the verified radix walk: 16-bit windowed pass + 2x 8-bit.
__global__ __launch_bounds__(1024) void k_select(
    const float* __restrict__ view, const float* __restrict__ proj,
    const float* __restrict__ occL,
    const unsigned* __restrict__ depthBits,
    const unsigned char* __restrict__ cnt8,
    const int* __restrict__ maxBlocksPtr,
    unsigned* __restrict__ sel,
    unsigned* __restrict__ tiedList,
    unsigned* __restrict__ tiedPrefX,
    unsigned* __restrict__ nTiedG)
{
    __shared__ float s_mvp[16];
    __shared__ unsigned s_h[WBINS];      // 16 KB hist (reused for 256-bin passes)
    __shared__ unsigned s_w[16];         // wave partials / offsets
    __shared__ unsigned s_wT[16], s_wMn[16], s_wMx[16];
    __shared__ unsigned s_tot, s_mn, s_mx, s_chTot;
    __shared__ unsigned s_found, s_prefix, s_remK;
    __shared__ unsigned s_list[256];
    __shared__ int s_n;
    __shared__ unsigned s_cntX[GX];

    int tid  = threadIdx.x;
    int lane = tid & 63;
    int wid  = tid >> 6;
    compute_mvp_lds(view, proj, s_mvp, tid);

    // ---- load all (depth, cnt) pairs into registers (static indexing) ----
    unsigned d[GPT], c[GPT];
    #pragma unroll
    for (int k = 0; k < GPT; ++k) {
        int g = tid + k * K2T;
        d[k] = depthBits[g];
        const uint4 cw = *(const uint4*)(cnt8 + (size_t)g * CSTR);
        c[k] = BSUM(cw.x) + BSUM(cw.y) + BSUM(cw.z);
    }

    // ---- reduce: total valid, min/max of top-16 depth bits (weighted) ----
    unsigned tot = 0, mn = 0xFFFFFFFFu, mx = 0;
    #pragma unroll
    for (int k = 0; k < GPT; ++k) {
        tot += c[k];
        if (c[k]) {
            unsigned hi = d[k] >> 16;
            mn = min(mn, hi);
            mx = max(mx, hi);
        }
    }
    for (int m = 1; m < 64; m <<= 1) {
        tot += (unsigned)__shfl_xor((int)tot, m);
        mn = min(mn, (unsigned)__shfl_xor((int)mn, m));
        mx = max(mx, (unsigned)__shfl_xor((int)mx, m));
    }
    if (lane == 0) { s_wT[wid] = tot; s_wMn[wid] = mn; s_wMx[wid] = mx; }
    __syncthreads();
    if (tid == 0) {
        unsigned t2 = 0, m2 = 0xFFFFFFFFu, x2 = 0;
        for (int w = 0; w < 16; ++w) {
            t2 += s_wT[w]; m2 = min(m2, s_wMn[w]); x2 = max(x2, s_wMx[w]);
        }
        s_tot = t2; s_mn = m2; s_mx = x2;
        s_found = 0;
    }
    __syncthreads();
    unsigned K = (unsigned)maxBlocksPtr[0];
    tot = s_tot; mn = s_mn; mx = s_mx;

    if (tot <= K) {                         // keep all valid
        if (tid == 0) {
            sel[0] = 0xFFFFFFFFu;
            sel[1] = 0x7FFFFFFFu;
            *nTiedG = 0u;
        }
        return;                             // uniform exit
    }

    // ---- pass A: 16-bit windowed histogram, chunks of WBINS ----
    unsigned remK = K;
    unsigned prefix = 0;
    unsigned span = mx - mn + 1u;
    unsigned nchunks = (span + WBINS - 1u) / WBINS;
    for (unsigned ch = 0; ch < nchunks; ++ch) {
        unsigned base = mn + ch * WBINS;
        #pragma unroll
        for (int j = 0; j < BPT; ++j) s_h[tid + j * K2T] = 0;
        __syncthreads();
        #pragma unroll
        for (int k = 0; k < GPT; ++k) {
            if (c[k]) {
                unsigned hi = d[k] >> 16;
                if (hi >= base && hi < base + WBINS)
                    atomicAdd(&s_h[hi - base], c[k]);
            }
        }
        __syncthreads();
        unsigned ps = 0;
        #pragma unroll
        for (int j = 0; j < BPT; ++j) ps += s_h[tid * BPT + j];
        unsigned iw = wave_incl_scan(ps, lane);
        if (lane == 63) s_w[wid] = iw;
        __syncthreads();
        if (wid == 0) {
            unsigned wv = (lane < 16) ? s_w[lane] : 0u;
            unsigned wiw = wave_incl_scan(wv, lane);
            if (lane < 16) s_w[lane] = wiw - wv;   // exclusive wave offset
            if (lane == 15) s_chTot = wiw;         // chunk total
        }
        __syncthreads();
        unsigned incl = iw + s_w[wid];
        unsigned chunkTot = s_chTot;
        unsigned excl = incl - ps;
        if (remK <= chunkTot && excl < remK && remK <= incl) {
            unsigned cum = excl;
            #pragma unroll
            for (int j = 0; j < BPT; ++j) {
                unsigned hv = s_h[tid * BPT + j];
                if (cum < remK && remK <= cum + hv) {
                    s_found  = 1u;
                    s_prefix = base + (unsigned)(tid * BPT + j);
                    s_remK   = remK - cum;
                }
                cum += hv;
            }
        }
        __syncthreads();
        if (s_found) { prefix = s_prefix; remK = s_remK; break; }
        remK -= chunkTot;                   // uniform
        __syncthreads();
    }

    // ---- passes B, C: 8-bit refine (bits 15..8 then 7..0) ----
    for (int p = 0; p < 2; ++p) {
        int matchShift = (p == 0) ? 16 : 8;
        int digitShift = (p == 0) ? 8 : 0;
        if (tid < 256) s_h[tid] = 0;
        __syncthreads();
        #pragma unroll
        for (int k = 0; k < GPT; ++k) {
            if (c[k] && (d[k] >> matchShift) == prefix)
                atomicAdd(&s_h[(d[k] >> digitShift) & 255u], c[k]);
        }
        __syncthreads();
        unsigned ps = (tid < 256) ? s_h[tid] : 0u;
        unsigned iw = wave_incl_scan(ps, lane);
        if (lane == 63) s_w[wid] = iw;
        __syncthreads();
        if (wid == 0) {
            unsigned wv = (lane < 16) ? s_w[lane] : 0u;
            unsigned wiw = wave_incl_scan(wv, lane);
            if (lane < 16) s_w[lane] = wiw - wv;
        }
        __syncthreads();
        unsigned incl = iw + s_w[wid];
        unsigned excl = incl - ps;
        if (excl < remK && remK <= incl) {   // unique crossing thread (tid<256)
            s_prefix = (prefix << 8) | (unsigned)tid;
            s_remK   = remK - excl;
        }
        __syncthreads();
        prefix = s_prefix; remK = s_remK;
        __syncthreads();
    }
    unsigned T = prefix;                     // final threshold depth bits
    unsigned R = remK;                       // quota at exactly T

    // ---- tied groups: list (sorted), per-x valid prefix ----
    if (tid == 0) s_n = 0;
    for (int x = tid; x < GX; x += K2T) s_cntX[x] = 0;
    __syncthreads();
    #pragma unroll
    for (int k = 0; k < GPT; ++k) {
        if (d[k] == T) {
            int idx = atomicAdd(&s_n, 1);
            if (idx < 256) s_list[idx] = (unsigned)(tid + k * K2T);
        }
    }
    __syncthreads();
    int n = min(s_n, 256);
    if (tid == 0) {
        for (int a = 1; a < n; ++a) {        // insertion sort (n tiny)
            unsigned v = s_list[a];
            int b = a - 1;
            while (b >= 0 && s_list[b] > v) { s_list[b + 1] = s_list[b]; --b; }
            s_list[b + 1] = v;
        }
    }
    __syncthreads();
    int pairs = GX * n;
    for (int pr = tid; pr < pairs; pr += K2T) {
        int x = pr / n;
        int s = pr - x * n;
        float occ;
        if (voxel_valid(x, (int)s_list[s], occL, s_mvp, &occ))
            atomicAdd(&s_cntX[x], 1u);
    }
    __syncthreads();
    if (tid == 0) {
        unsigned run = 0;
        for (int x = 0; x < GX; ++x) { tiedPrefX[x] = run; run += s_cntX[x]; }
        *nTiedG = (unsigned)n;
        sel[0] = T;
        sel[1] = R;
    }
    if (tid < n) tiedList[tid] = s_list[tid];
}

// K3: output. NEW vs R5: groups with depth > T can't be kept regardless of
// validity -> skip occL read + expf entirely and write zeros (~94% of voxels).
__global__ __launch_bounds__(256) void k_out(
    const float* __restrict__ occL,
    const float* __restrict__ matL,
    const float* __restrict__ mvp,
    const unsigned* __restrict__ depthBits,
    const unsigned* __restrict__ sel,
    const unsigned* __restrict__ tiedList,
    const unsigned* __restrict__ tiedPrefX,
    const unsigned* __restrict__ nTiedPtr,
    float* __restrict__ out)
{
    int i = blockIdx.x * 256 + threadIdx.x;
    if (i >= NVOX) return;
    int x = i / GRP;                         // wave-uniform
    int g = i - x * GRP;

    unsigned T  = sel[0];
    unsigned db = depthBits[g];

    f4 o0 = (f4)(0.0f);
    f4 o1 = (f4)(0.0f);

    if (db <= T) {                           // only these can possibly be kept
        float occ;
        bool valid = voxel_valid(x, g, occL, mvp, &occ);
        bool keep = false;
        if (valid) {
            if (db < T) {
                keep = true;
            } else {                         // db == T: index-order tie break
                unsigned R = sel[1];
                unsigned rank = tiedPrefX[x];
                int n = (int)*nTiedPtr;
                for (int s = 0; s < n; ++s) {
                    unsigned gs = tiedList[s];
                    if (gs >= (unsigned)g) break;
                    float o2;
                    if (voxel_valid(x, (int)gs, occL, mvp, &o2)) ++rank;
                }
                keep = rank < R;
            }
        }
        if (keep) {
            const f4* mp = reinterpret_cast<const f4*>(matL) + (size_t)i * 2;
            f4 a = __builtin_nontemporal_load(mp);
            f4 b = __builtin_nontemporal_load(mp + 1);
            float mx = fmaxf(fmaxf(fmaxf(a[0], a[1]), fmaxf(a[2], a[3])),
                             fmaxf(fmaxf(b[0], b[1]), fmaxf(b[2], b[3])));
            float e0 = expf(a[0] - mx), e1 = expf(a[1] - mx), e2 = expf(a[2] - mx), e3 = expf(a[3] - mx);
            float e4 = expf(b[0] - mx), e5 = expf(b[1] - mx), e6 = expf(b[2] - mx), e7 = expf(b[3] - mx);
            float s = ((e0 + e1) + (e2 + e3)) + ((e4 + e5) + (e6 + e7));
            float inv = occ / s;
            o0[0] = e0 * inv; o0[1] = e1 * inv; o0[2] = e2 * inv; o0[3] = e3 * inv;
            o1[0] = e4 * inv; o1[1] = e5 * inv; o1[2] = e6 * inv; o1[3] = e7 * inv;
        }
    }
    f4* op = reinterpret_cast<f4*>(out) + (size_t)i * 2;
    __builtin_nontemporal_store(o0, op);
    __builtin_nontemporal_store(o1, op + 1);
}

extern "C" void kernel_launch(void* const* d_in, const int* in_sizes, int n_in,
                              void* d_out, int out_size, void* d_ws, size_t ws_size,
                              hipStream_t stream)
{
    const float* occL = (const float*)d_in[0];
    const float* matL = (const float*)d_in[1];
    const float* view = (const float*)d_in[2];
    const float* proj = (const float*)d_in[3];
    const int*   mb   = (const int*)d_in[4];

    char* ws = (char*)d_ws;
    float*          mvp      = (float*)(ws + WS_MVP);
    unsigned*       depthB   = (unsigned*)(ws + WS_DEPTH);
    unsigned char*  cnt8     = (unsigned char*)(ws + WS_CNT8);
    unsigned*       sel      = (unsigned*)(ws + WS_SEL);
    unsigned*       tiedList = (unsigned*)(ws + WS_TLIST);
    unsigned*       tiedPref = (unsigned*)(ws + WS_TPREF);
    unsigned*       nTied    = (unsigned*)(ws + WS_NTIED);

    k_prep_count<<<NXC * GBLK, 256, 0, stream>>>(view, proj, occL, mvp, depthB, cnt8);
    k_select<<<1, K2T, 0, stream>>>(view, proj, occL, depthB, cnt8, mb,
                                    sel, tiedList, tiedPref, nTied);
    k_out<<<NVOX / 256, 256, 0, stream>>>(occL, matL, mvp, depthB, sel,
                                          tiedList, tiedPref, nTied, (float*)d_out);
}

// Round 9
// 66.794 us; speedup vs baseline: 4.4767x; 1.0389x over previous
//
#include <hip/hip_runtime.h>

#define GX 192
#define GY 96
#define GZ 192
#define GRP (GY*GZ)            // 18432 (y,z) groups
#define NVOX (GX*GRP)          // 3538944 voxels

#define NXC 12                 // x-chunks
#define XCW (GX/NXC)           // 16 voxels per thread/chunk
#define GBLK (GRP/256)         // 72 blocks per chunk

#define K2T 1024               // select kernel threads
#define GPT (GRP/K2T)          // 18 groups per thread
#define WBINS 4096             // window chunk bins (16-bit pass)
#define BPT (WBINS/K2T)        // 4 bins per thread

// workspace byte offsets
#define WS_MVP    0                        // 16 floats
#define WS_G16    64                       // GRP x 16B records {u32 depth, u8 cnt[12]}
#define WS_DEPTH  (WS_G16 + GRP*16)        // GRP u32 depth bits (dense copy for k_out)
#define WS_SEL    (WS_DEPTH + GRP*4)       // 2 u32: T, R
#define WS_TLIST  (WS_SEL + 16)            // 256 u32 tied group ids (sorted)
#define WS_TPREF  (WS_TLIST + 1024)        // GX u32 excl prefix of tied-valid per x
#define WS_NTIED  (WS_TPREF + GX*4)        // 1 u32

typedef float f4 __attribute__((ext_vector_type(4)));

#define BSUM(w) (((w) & 255u) + (((w) >> 8) & 255u) + (((w) >> 16) & 255u) + ((w) >> 24))

// Replicate reference fp32 arithmetic exactly:
//   clip_c = fma(cz, M[c][2], fma(cy, M[c][1], cx*M[c][0])) + M[c][3]
__device__ __forceinline__ bool voxel_valid(int x, int g,
                                            const float* __restrict__ occL,
                                            const float* M,
                                            float* occ_out)
{
    int y = g / GZ;
    int z = g - y * GZ;
    float cx = (float)(2 * x - 191);
    float cy = (float)(2 * y + 1);
    float cz = (float)(2 * z - 191);

    float logit = occL[(size_t)x * GRP + g];
    float occ = 1.0f / (1.0f + expf(-logit));
    *occ_out = occ;
    if (!(occ > 0.01f)) return false;

    float c0 = __fadd_rn(__fmaf_rn(cz, M[2],  __fmaf_rn(cy, M[1],  __fmul_rn(cx, M[0]))),  M[3]);
    float c1 = __fadd_rn(__fmaf_rn(cz, M[6],  __fmaf_rn(cy, M[5],  __fmul_rn(cx, M[4]))),  M[7]);
    float c2 = __fadd_rn(__fmaf_rn(cz, M[10], __fmaf_rn(cy, M[9],  __fmul_rn(cx, M[8]))),  M[11]);
    float c3 = __fadd_rn(__fmaf_rn(cz, M[14], __fmaf_rn(cy, M[13], __fmul_rn(cx, M[12]))), M[15]);

    float w  = fmaxf(c3, 1e-6f);
    float nx = c0 / w;
    float ny = c1 / w;
    float nz = c2 / w;
    return (nx >= -1.0f) && (nx <= 1.0f) &&
           (ny >= -1.0f) && (ny <= 1.0f) &&
           (nz >= -1.0f) && (nz <= 1.0f);
}

__device__ __forceinline__ void compute_mvp_lds(const float* view, const float* proj,
                                                float* s_mvp, int tid)
{
    if (tid < 16) {
        int r = tid >> 2, c = tid & 3;
        float acc = 0.0f;
        for (int k = 0; k < 4; ++k)
            acc = __fadd_rn(acc, __fmul_rn(proj[r * 4 + k], view[k * 4 + c]));
        s_mvp[tid] = acc;
    }
}

__device__ __forceinline__ unsigned wave_incl_scan(unsigned v, int lane)
{
    #pragma unroll
    for (int off = 1; off < 64; off <<= 1) {
        unsigned u = (unsigned)__shfl_up((int)v, off);
        if (lane >= off) v += u;
    }
    return v;
}

// K1: mvp (block 0 -> ws), depth bits (xc==0, into record + dense array),
// u8 partial valid counts per x-chunk into byte 4+xc of the 16B group record.
// grid = NXC * GBLK = 864 blocks of 256. NT stores keep data out of remote L2s.
__global__ __launch_bounds__(256) void k_prep_count(
    const float* __restrict__ view, const float* __restrict__ proj,
    const float* __restrict__ occL,
    float* __restrict__ mvpOut,
    unsigned char* __restrict__ g16,       // GRP x 16B records
    unsigned* __restrict__ depthBits)
{
    __shared__ float s_mvp[16];
    int tid = threadIdx.x;
    compute_mvp_lds(view, proj, s_mvp, tid);
    __syncthreads();

    int b  = blockIdx.x;
    int gb = b % GBLK;
    int xc = b / GBLK;
    int g  = gb * 256 + tid;

    if (b == 0 && tid < 16) mvpOut[tid] = s_mvp[tid];

    if (xc == 0) {
        int y = g / GZ;
        int z = g - y * GZ;
        float cy = (float)(2 * y + 1);
        float cz = (float)(2 * z - 191);
        float seed = __fmul_rn(-191.0f, view[8]);
        float vz = __fadd_rn(__fmaf_rn(cz, view[10], __fmaf_rn(cy, view[9], seed)), view[11]);
        float d  = fmaxf(-vz, 0.0f);
        unsigned db = __float_as_uint(d);          // d >= 0: bits order-monotone
        __builtin_nontemporal_store(db, (unsigned*)(g16 + (size_t)g * 16));
        __builtin_nontemporal_store(db, &depthBits[g]);
    }

    unsigned c = 0;
    int x0 = xc * XCW;
    #pragma unroll
    for (int j = 0; j < XCW; ++j) {
        float occ;
        if (voxel_valid(x0 + j, g, occL, s_mvp, &occ)) ++c;
    }
    __builtin_nontemporal_store((unsigned char)c, g16 + (size_t)g * 16 + 4 + xc);
}

// K2: full weighted selection + tied-group prep in ONE block of 1024 threads.
// One uint4 load per group (depth + counts packed); load-all-then-process for MLP.
// Integer-identical to the verified radix walk: 16-bit windowed pass + 2x 8-bit.
__global__ __launch_bounds__(1024) void k_select(
    const float* __restrict__ view, const float* __restrict__ proj,
    const float* __restrict__ occL,
    const unsigned char* __restrict__ g16,
    const int* __restrict__ maxBlocksPtr,
    unsigned* __restrict__ sel,
    unsigned* __restrict__ tiedList,
    unsigned* __restrict__ tiedPrefX,
    unsigned* __restrict__ nTiedG)
{
    __shared__ float s_mvp[16];
    __shared__ unsigned s_h[WBINS];      // 16 KB hist (reused for 256-bin passes)
    __shared__ unsigned s_w[16];         // wave partials / offsets
    __shared__ unsigned s_wT[16], s_wMn[16], s_wMx[16];
    __shared__ unsigned s_tot, s_mn, s_mx, s_chTot;
    __shared__ unsigned s_found, s_prefix, s_remK;
    __shared__ unsigned s_list[256];
    __shared__ int s_n;
    __shared__ unsigned s_cntX[GX];

    int tid  = threadIdx.x;
    int lane = tid & 63;
    int wid  = tid >> 6;
    compute_mvp_lds(view, proj, s_mvp, tid);

    // ---- batch-load all group records (one uint4 each), then extract ----
    uint4 q[GPT];
    #pragma unroll
    for (int k = 0; k < GPT; ++k)
        q[k] = *(const uint4*)(g16 + (size_t)(tid + k * K2T) * 16);

    unsigned d[GPT], c[GPT];
    #pragma unroll
    for (int k = 0; k < GPT; ++k) {
        d[k] = q[k].x;
        c[k] = BSUM(q[k].y) + BSUM(q[k].z) + BSUM(q[k].w);
    }

    // ---- reduce: total valid, min/max of top-16 depth bits (weighted) ----
    unsigned tot = 0, mn = 0xFFFFFFFFu, mx = 0;
    #pragma unroll
    for (int k = 0; k < GPT; ++k) {
        tot += c[k];
        if (c[k]) {
            unsigned hi = d[k] >> 16;
            mn = min(mn, hi);
            mx = max(mx, hi);
        }
    }
    for (int m = 1; m < 64; m <<= 1) {
        tot += (unsigned)__shfl_xor((int)tot, m);
        mn = min(mn, (unsigned)__shfl_xor((int)mn, m));
        mx = max(mx, (unsigned)__shfl_xor((int)mx, m));
    }
    if (lane == 0) { s_wT[wid] = tot; s_wMn[wid] = mn; s_wMx[wid] = mx; }
    __syncthreads();
    if (tid == 0) {
        unsigned t2 = 0, m2 = 0xFFFFFFFFu, x2 = 0;
        for (int w = 0; w < 16; ++w) {
            t2 += s_wT[w]; m2 = min(m2, s_wMn[w]); x2 = max(x2, s_wMx[w]);
        }
        s_tot = t2; s_mn = m2; s_mx = x2;
        s_found = 0;
    }
    __syncthreads();
    unsigned K = (unsigned)maxBlocksPtr[0];
    tot = s_tot; mn = s_mn; mx = s_mx;

    if (tot <= K) {                         // keep all valid
        if (tid == 0) {
            sel[0] = 0xFFFFFFFFu;
            sel[1] = 0x7FFFFFFFu;
            *nTiedG = 0u;
        }
        return;                             // uniform exit
    }

    // ---- pass A: 16-bit windowed histogram, chunks of WBINS ----
    unsigned remK = K;
    unsigned prefix = 0;
    unsigned span = mx - mn + 1u;
    unsigned nchunks = (span + WBINS - 1u) / WBINS;
    for (unsigned ch = 0; ch < nchunks; ++ch) {
        unsigned base = mn + ch * WBINS;
        #pragma unroll
        for (int j = 0; j < BPT; ++j) s_h[tid + j * K2T] = 0;
        __syncthreads();
        #pragma unroll
        for (int k = 0; k < GPT; ++k) {
            if (c[k]) {
                unsigned hi = d[k] >> 16;
                if (hi >= base && hi < base + WBINS)
                    atomicAdd(&s_h[hi - base], c[k]);
            }
        }
        __syncthreads();
        unsigned ps = 0;
        #pragma unroll
        for (int j = 0; j < BPT; ++j) ps += s_h[tid * BPT + j];
        unsigned iw = wave_incl_scan(ps, lane);
        if (lane == 63) s_w[wid] = iw;
        __syncthreads();
        if (wid == 0) {
            unsigned wv = (lane < 16) ? s_w[lane] : 0u;
            unsigned wiw = wave_incl_scan(wv, lane);
            if (lane < 16) s_w[lane] = wiw - wv;   // exclusive wave offset
            if (lane == 15) s_chTot = wiw;         // chunk total
        }
        __syncthreads();
        unsigned incl = iw + s_w[wid];
        unsigned chunkTot = s_chTot;
        unsigned excl = incl - ps;
        if (remK <= chunkTot && excl < remK && remK <= incl) {
            unsigned cum = excl;
            #pragma unroll
            for (int j = 0; j < BPT; ++j) {
                unsigned hv = s_h[tid * BPT + j];
                if (cum < remK && remK <= cum + hv) {
                    s_found  = 1u;
                    s_prefix = base + (unsigned)(tid * BPT + j);
                    s_remK   = remK - cum;
                }
                cum += hv;
            }
        }
        __syncthreads();
        if (s_found) { prefix = s_prefix; remK = s_remK; break; }
        remK -= chunkTot;                   // uniform
        __syncthreads();
    }

    // ---- passes B, C: 8-bit refine (bits 15..8 then 7..0) ----
    for (int p = 0; p < 2; ++p) {
        int matchShift = (p == 0) ? 16 : 8;
        int digitShift = (p == 0) ? 8 : 0;
        if (tid < 256) s_h[tid] = 0;
        __syncthreads();
        #pragma unroll
        for (int k = 0; k < GPT; ++k) {
            if (c[k] && (d[k] >> matchShift) == prefix)
                atomicAdd(&s_h[(d[k] >> digitShift) & 255u], c[k]);
        }
        __syncthreads();
        unsigned ps = (tid < 256) ? s_h[tid] : 0u;
        unsigned iw = wave_incl_scan(ps, lane);
        if (lane == 63) s_w[wid] = iw;
        __syncthreads();
        if (wid == 0) {
            unsigned wv = (lane < 16) ? s_w[lane] : 0u;
            unsigned wiw = wave_incl_scan(wv, lane);
            if (lane < 16) s_w[lane] = wiw - wv;
        }
        __syncthreads();
        unsigned incl = iw + s_w[wid];
        unsigned excl = incl - ps;
        if (excl < remK && remK <= incl) {   // unique crossing thread (tid<256)
            s_prefix = (prefix << 8) | (unsigned)tid;
            s_remK   = remK - excl;
        }
        __syncthreads();
        prefix = s_prefix; remK = s_remK;
        __syncthreads();
    }
    unsigned T = prefix;                     // final threshold depth bits
    unsigned R = remK;                       // quota at exactly T

    // ---- tied groups: list (sorted), per-x valid prefix ----
    if (tid == 0) s_n = 0;
    for (int x = tid; x < GX; x += K2T) s_cntX[x] = 0;
    __syncthreads();
    #pragma unroll
    for (int k = 0; k < GPT; ++k) {
        if (d[k] == T) {
            int idx = atomicAdd(&s_n, 1);
            if (idx < 256) s_list[idx] = (unsigned)(tid + k * K2T);
        }
    }
    __syncthreads();
    int n = min(s_n, 256);
    if (tid == 0) {
        for (int a = 1; a < n; ++a) {        // insertion sort (n tiny)
            unsigned v = s_list[a];
            int b = a - 1;
            while (b >= 0 && s_list[b] > v) { s_list[b + 1] = s_list[b]; --b; }
            s_list[b + 1] = v;
        }
    }
    __syncthreads();
    int pairs = GX * n;
    for (int pr = tid; pr < pairs; pr += K2T) {
        int x = pr / n;
        int s = pr - x * n;
        float occ;
        if (voxel_valid(x, (int)s_list[s], occL, s_mvp, &occ))
            atomicAdd(&s_cntX[x], 1u);
    }
    __syncthreads();
    if (tid == 0) {
        unsigned run = 0;
        for (int x = 0; x < GX; ++x) { tiedPrefX[x] = run; run += s_cntX[x]; }
        *nTiedG = (unsigned)n;
        sel[0] = T;
        sel[1] = R;
    }
    if (tid < n) tiedList[tid] = s_list[tid];
}

// K3: output — R5-exact body (recompute predicate from occL; NT loads/stores).
__global__ __launch_bounds__(256) void k_out(
    const float* __restrict__ occL,
    const float* __restrict__ matL,
    const float* __restrict__ mvp,
    const unsigned* __restrict__ depthBits,
    const unsigned* __restrict__ sel,
    const unsigned* __restrict__ tiedList,
    const unsigned* __restrict__ tiedPrefX,
    const unsigned* __restrict__ nTiedPtr,
    float* __restrict__ out)
{
    int i = blockIdx.x * 256 + threadIdx.x;
    if (i >= NVOX) return;
    int x = i / GRP;
    int g = i - x * GRP;

    float occ;
    bool valid = voxel_valid(x, g, occL, mvp, &occ);
    bool keep = false;
    if (valid) {
        unsigned T  = sel[0];
        unsigned db = depthBits[g];
        if (db < T) {
            keep = true;
        } else if (db == T) {
            unsigned R = sel[1];
            unsigned rank = tiedPrefX[x];
            int n = (int)*nTiedPtr;
            for (int s = 0; s < n; ++s) {
                unsigned gs = tiedList[s];
                if (gs >= (unsigned)g) break;
                float o2;
                if (voxel_valid(x, (int)gs, occL, mvp, &o2)) ++rank;
            }
            keep = rank < R;
        }
    }

    f4 o0 = (f4)(0.0f);
    f4 o1 = (f4)(0.0f);
    if (keep) {
        const f4* mp = reinterpret_cast<const f4*>(matL) + (size_t)i * 2;
        f4 a = __builtin_nontemporal_load(mp);
        f4 b = __builtin_nontemporal_load(mp + 1);
        float mx = fmaxf(fmaxf(fmaxf(a[0], a[1]), fmaxf(a[2], a[3])),
                         fmaxf(fmaxf(b[0], b[1]), fmaxf(b[2], b[3])));
        float e0 = expf(a[0] - mx), e1 = expf(a[1] - mx), e2 = expf(a[2] - mx), e3 = expf(a[3] - mx);
        float e4 = expf(b[0] - mx), e5 = expf(b[1] - mx), e6 = expf(b[2] - mx), e7 = expf(b[3] - mx);
        float s = ((e0 + e1) + (e2 + e3)) + ((e4 + e5) + (e6 + e7));
        float inv = occ / s;
        o0[0] = e0 * inv; o0[1] = e1 * inv; o0[2] = e2 * inv; o0[3] = e3 * inv;
        o1[0] = e4 * inv; o1[1] = e5 * inv; o1[2] = e6 * inv; o1[3] = e7 * inv;
    }
    f4* op = reinterpret_cast<f4*>(out) + (size_t)i * 2;
    __builtin_nontemporal_store(o0, op);
    __builtin_nontemporal_store(o1, op + 1);
}

extern "C" void kernel_launch(void* const* d_in, const int* in_sizes, int n_in,
                              void* d_out, int out_size, void* d_ws, size_t ws_size,
                              hipStream_t stream)
{
    const float* occL = (const float*)d_in[0];
    const float* matL = (const float*)d_in[1];
    const float* view = (const float*)d_in[2];
    const float* proj = (const float*)d_in[3];
    const int*   mb   = (const int*)d_in[4];

    char* ws = (char*)d_ws;
    float*          mvp      = (float*)(ws + WS_MVP);
    unsigned char*  g16      = (unsigned char*)(ws + WS_G16);
    unsigned*       depthB   = (unsigned*)(ws + WS_DEPTH);
    unsigned*       sel      = (unsigned*)(ws + WS_SEL);
    unsigned*       tiedList = (unsigned*)(ws + WS_TLIST);
    unsigned*       tiedPref = (unsigned*)(ws + WS_TPREF);
    unsigned*       nTied    = (unsigned*)(ws + WS_NTIED);

    k_prep_count<<<NXC * GBLK, 256, 0, stream>>>(view, proj, occL, mvp, g16, depthB);
    k_select<<<1, K2T, 0, stream>>>(view, proj, occL, g16, mb,
                                    sel, tiedList, tiedPref, nTied);
    k_out<<<NVOX / 256, 256, 0, stream>>>(occL, matL, mvp, depthB, sel,
                                          tiedList, tiedPref, nTied, (float*)d_out);
}

// Round 10
// 66.135 us; speedup vs baseline: 4.5213x; 1.0100x over previous
//
#include <hip/hip_runtime.h>

#define GX 192
#define GY 96
#define GZ 192
#define GRP (GY*GZ)            // 18432 (y,z) groups
#define NVOX (GX*GRP)          // 3538944 voxels

#define NXC 12                 // x-chunks
#define XCW (GX/NXC)           // 16 voxels per thread/chunk
#define GBLK (GRP/256)         // 72 blocks per chunk

#define K2T 1024               // select kernel threads
#define GPT (GRP/K2T)          // 18 groups per thread
#define WBINS 4096             // window chunk bins (16-bit pass)
#define BPT (WBINS/K2T)        // 4 bins per thread

// workspace byte offsets
#define WS_MVP    0                        // 16 floats
#define WS_G16    64                       // GRP x 16B records {u32 depth, u8 cnt[12]}
#define WS_DEPTH  (WS_G16 + GRP*16)        // GRP u32 depth bits (dense copy for k_out)
#define WS_SEL    (WS_DEPTH + GRP*4)       // 2 u32: T, R
#define WS_TLIST  (WS_SEL + 16)            // 256 u32 tied group ids (sorted)
#define WS_TPREF  (WS_TLIST + 1024)        // GX u32 excl prefix of tied-valid per x
#define WS_NTIED  (WS_TPREF + GX*4)        // 1 u32

typedef float f4 __attribute__((ext_vector_type(4)));

#define BSUM(w) (((w) & 255u) + (((w) >> 8) & 255u) + (((w) >> 16) & 255u) + ((w) >> 24))

// Replicate reference fp32 arithmetic exactly:
//   clip_c = fma(cz, M[c][2], fma(cy, M[c][1], cx*M[c][0])) + M[c][3]
__device__ __forceinline__ bool voxel_valid(int x, int g,
                                            const float* __restrict__ occL,
                                            const float* M,
                                            float* occ_out)
{
    int y = g / GZ;
    int z = g - y * GZ;
    float cx = (float)(2 * x - 191);
    float cy = (float)(2 * y + 1);
    float cz = (float)(2 * z - 191);

    float logit = occL[(size_t)x * GRP + g];
    float occ = 1.0f / (1.0f + expf(-logit));
    *occ_out = occ;
    if (!(occ > 0.01f)) return false;

    float c0 = __fadd_rn(__fmaf_rn(cz, M[2],  __fmaf_rn(cy, M[1],  __fmul_rn(cx, M[0]))),  M[3]);
    float c1 = __fadd_rn(__fmaf_rn(cz, M[6],  __fmaf_rn(cy, M[5],  __fmul_rn(cx, M[4]))),  M[7]);
    float c2 = __fadd_rn(__fmaf_rn(cz, M[10], __fmaf_rn(cy, M[9],  __fmul_rn(cx, M[8]))),  M[11]);
    float c3 = __fadd_rn(__fmaf_rn(cz, M[14], __fmaf_rn(cy, M[13], __fmul_rn(cx, M[12]))), M[15]);

    float w  = fmaxf(c3, 1e-6f);
    float nx = c0 / w;
    float ny = c1 / w;
    float nz = c2 / w;
    return (nx >= -1.0f) && (nx <= 1.0f) &&
           (ny >= -1.0f) && (ny <= 1.0f) &&
           (nz >= -1.0f) && (nz <= 1.0f);
}

__device__ __forceinline__ void compute_mvp_lds(const float* view, const float* proj,
                                                float* s_mvp, int tid)
{
    if (tid < 16) {
        int r = tid >> 2, c = tid & 3;
        float acc = 0.0f;
        for (int k = 0; k < 4; ++k)
            acc = __fadd_rn(acc, __fmul_rn(proj[r * 4 + k], view[k * 4 + c]));
        s_mvp[tid] = acc;
    }
}

__device__ __forceinline__ unsigned wave_incl_scan(unsigned v, int lane)
{
    #pragma unroll
    for (int off = 1; off < 64; off <<= 1) {
        unsigned u = (unsigned)__shfl_up((int)v, off);
        if (lane >= off) v += u;
    }
    return v;
}

// K1: mvp (block 0 -> ws), depth bits (xc==0, into record + dense array),
// u8 partial valid counts per x-chunk into byte 4+xc of the 16B group record.
// grid = NXC * GBLK = 864 blocks of 256. Normal stores (L2 write-combining;
// byte-granular dirty tracking merges cross-XCD byte writes -- proven R4/R5).
__global__ __launch_bounds__(256) void k_prep_count(
    const float* __restrict__ view, const float* __restrict__ proj,
    const float* __restrict__ occL,
    float* __restrict__ mvpOut,
    unsigned char* __restrict__ g16,       // GRP x 16B records
    unsigned* __restrict__ depthBits)
{
    __shared__ float s_mvp[16];
    int tid = threadIdx.x;
    compute_mvp_lds(view, proj, s_mvp, tid);
    __syncthreads();

    int b  = blockIdx.x;
    int gb = b % GBLK;
    int xc = b / GBLK;
    int g  = gb * 256 + tid;

    if (b == 0 && tid < 16) mvpOut[tid] = s_mvp[tid];

    if (xc == 0) {
        int y = g / GZ;
        int z = g - y * GZ;
        float cy = (float)(2 * y + 1);
        float cz = (float)(2 * z - 191);
        float seed = __fmul_rn(-191.0f, view[8]);
        float vz = __fadd_rn(__fmaf_rn(cz, view[10], __fmaf_rn(cy, view[9], seed)), view[11]);
        float d  = fmaxf(-vz, 0.0f);
        unsigned db = __float_as_uint(d);          // d >= 0: bits order-monotone
        *(unsigned*)(g16 + (size_t)g * 16) = db;
        depthBits[g] = db;
    }

    unsigned c = 0;
    int x0 = xc * XCW;
    #pragma unroll
    for (int j = 0; j < XCW; ++j) {
        float occ;
        if (voxel_valid(x0 + j, g, occL, s_mvp, &occ)) ++c;
    }
    g16[(size_t)g * 16 + 4 + xc] = (unsigned char)c;
}

// K2: full weighted selection + tied-group prep in ONE block of 1024 threads.
// One uint4 load per group (depth + counts packed); load-all-then-process for MLP.
// Integer-identical to the verified radix walk: 16-bit windowed pass + 2x 8-bit.
__global__ __launch_bounds__(1024) void k_select(
    const float* __restrict__ view, const float* __restrict__ proj,
    const float* __restrict__ occL,
    const unsigned char* __restrict__ g16,
    const int* __restrict__ maxBlocksPtr,
    unsigned* __restrict__ sel,
    unsigned* __restrict__ tiedList,
    unsigned* __restrict__ tiedPrefX,
    unsigned* __restrict__ nTiedG)
{
    __shared__ float s_mvp[16];
    __shared__ unsigned s_h[WBINS];      // 16 KB hist (reused for 256-bin passes)
    __shared__ unsigned s_w[16];         // wave partials / offsets
    __shared__ unsigned s_wT[16], s_wMn[16], s_wMx[16];
    __shared__ unsigned s_tot, s_mn, s_mx, s_chTot;
    __shared__ unsigned s_found, s_prefix, s_remK;
    __shared__ unsigned s_list[256];
    __shared__ int s_n;
    __shared__ unsigned s_cntX[GX];

    int tid  = threadIdx.x;
    int lane = tid & 63;
    int wid  = tid >> 6;
    compute_mvp_lds(view, proj, s_mvp, tid);

    // ---- batch-load all group records (one uint4 each), then extract ----
    uint4 q[GPT];
    #pragma unroll
    for (int k = 0; k < GPT; ++k)
        q[k] = *(const uint4*)(g16 + (size_t)(tid + k * K2T) * 16);

    unsigned d[GPT], c[GPT];
    #pragma unroll
    for (int k = 0; k < GPT; ++k) {
        d[k] = q[k].x;
        c[k] = BSUM(q[k].y) + BSUM(q[k].z) + BSUM(q[k].w);
    }

    // ---- reduce: total valid, min/max of top-16 depth bits (weighted) ----
    unsigned tot = 0, mn = 0xFFFFFFFFu, mx = 0;
    #pragma unroll
    for (int k = 0; k < GPT; ++k) {
        tot += c[k];
        if (c[k]) {
            unsigned hi = d[k] >> 16;
            mn = min(mn, hi);
            mx = max(mx, hi);
        }
    }
    for (int m = 1; m < 64; m <<= 1) {
        tot += (unsigned)__shfl_xor((int)tot, m);
        mn = min(mn, (unsigned)__shfl_xor((int)mn, m));
        mx = max(mx, (unsigned)__shfl_xor((int)mx, m));
    }
    if (lane == 0) { s_wT[wid] = tot; s_wMn[wid] = mn; s_wMx[wid] = mx; }
    __syncthreads();
    if (tid == 0) {
        unsigned t2 = 0, m2 = 0xFFFFFFFFu, x2 = 0;
        for (int w = 0; w < 16; ++w) {
            t2 += s_wT[w]; m2 = min(m2, s_wMn[w]); x2 = max(x2, s_wMx[w]);
        }
        s_tot = t2; s_mn = m2; s_mx = x2;
        s_found = 0;
    }
    __syncthreads();
    unsigned K = (unsigned)maxBlocksPtr[0];
    tot = s_tot; mn = s_mn; mx = s_mx;

    if (tot <= K) {                         // keep all valid
        if (tid == 0) {
            sel[0] = 0xFFFFFFFFu;
            sel[1] = 0x7FFFFFFFu;
            *nTiedG = 0u;
        }
        return;                             // uniform exit
    }

    // ---- pass A: 16-bit windowed histogram, chunks of WBINS ----
    unsigned remK = K;
    unsigned prefix = 0;
    unsigned span = mx - mn + 1u;
    unsigned nchunks = (span + WBINS - 1u) / WBINS;
    for (unsigned ch = 0; ch < nchunks; ++ch) {
        unsigned base = mn + ch * WBINS;
        #pragma unroll
        for (int j = 0; j < BPT; ++j) s_h[tid + j * K2T] = 0;
        __syncthreads();
        #pragma unroll
        for (int k = 0; k < GPT; ++k) {
            if (c[k]) {
                unsigned hi = d[k] >> 16;
                if (hi >= base && hi < base + WBINS)
                    atomicAdd(&s_h[hi - base], c[k]);
            }
        }
        __syncthreads();
        unsigned ps = 0;
        #pragma unroll
        for (int j = 0; j < BPT; ++j) ps += s_h[tid * BPT + j];
        unsigned iw = wave_incl_scan(ps, lane);
        if (lane == 63) s_w[wid] = iw;
        __syncthreads();
        if (wid == 0) {
            unsigned wv = (lane < 16) ? s_w[lane] : 0u;
            unsigned wiw = wave_incl_scan(wv, lane);
            if (lane < 16) s_w[lane] = wiw - wv;   // exclusive wave offset
            if (lane == 15) s_chTot = wiw;         // chunk total
        }
        __syncthreads();
        unsigned incl = iw + s_w[wid];
        unsigned chunkTot = s_chTot;
        unsigned excl = incl - ps;
        if (remK <= chunkTot && excl < remK && remK <= incl) {
            unsigned cum = excl;
            #pragma unroll
            for (int j = 0; j < BPT; ++j) {
                unsigned hv = s_h[tid * BPT + j];
                if (cum < remK && remK <= cum + hv) {
                    s_found  = 1u;
                    s_prefix = base + (unsigned)(tid * BPT + j);
                    s_remK   = remK - cum;
                }
                cum += hv;
            }
        }
        __syncthreads();
        if (s_found) { prefix = s_prefix; remK = s_remK; break; }
        remK -= chunkTot;                   // uniform
        __syncthreads();
    }

    // ---- passes B, C: 8-bit refine (bits 15..8 then 7..0) ----
    for (int p = 0; p < 2; ++p) {
        int matchShift = (p == 0) ? 16 : 8;
        int digitShift = (p == 0) ? 8 : 0;
        if (tid < 256) s_h[tid] = 0;
        __syncthreads();
        #pragma unroll
        for (int k = 0; k < GPT; ++k) {
            if (c[k] && (d[k] >> matchShift) == prefix)
                atomicAdd(&s_h[(d[k] >> digitShift) & 255u], c[k]);
        }
        __syncthreads();
        unsigned ps = (tid < 256) ? s_h[tid] : 0u;
        unsigned iw = wave_incl_scan(ps, lane);
        if (lane == 63) s_w[wid] = iw;
        __syncthreads();
        if (wid == 0) {
            unsigned wv = (lane < 16) ? s_w[lane] : 0u;
            unsigned wiw = wave_incl_scan(wv, lane);
            if (lane < 16) s_w[lane] = wiw - wv;
        }
        __syncthreads();
        unsigned incl = iw + s_w[wid];
        unsigned excl = incl - ps;
        if (excl < remK && remK <= incl) {   // unique crossing thread (tid<256)
            s_prefix = (prefix << 8) | (unsigned)tid;
            s_remK   = remK - excl;
        }
        __syncthreads();
        prefix = s_prefix; remK = s_remK;
        __syncthreads();
    }
    unsigned T = prefix;                     // final threshold depth bits
    unsigned R = remK;                       // quota at exactly T

    // ---- tied groups: list (sorted), per-x valid prefix ----
    if (tid == 0) s_n = 0;
    for (int x = tid; x < GX; x += K2T) s_cntX[x] = 0;
    __syncthreads();
    #pragma unroll
    for (int k = 0; k < GPT; ++k) {
        if (d[k] == T) {
            int idx = atomicAdd(&s_n, 1);
            if (idx < 256) s_list[idx] = (unsigned)(tid + k * K2T);
        }
    }
    __syncthreads();
    int n = min(s_n, 256);
    if (tid == 0) {
        for (int a = 1; a < n; ++a) {        // insertion sort (n tiny)
            unsigned v = s_list[a];
            int b = a - 1;
            while (b >= 0 && s_list[b] > v) { s_list[b + 1] = s_list[b]; --b; }
            s_list[b + 1] = v;
        }
    }
    __syncthreads();
    int pairs = GX * n;
    for (int pr = tid; pr < pairs; pr += K2T) {
        int x = pr / n;
        int s = pr - x * n;
        float occ;
        if (voxel_valid(x, (int)s_list[s], occL, s_mvp, &occ))
            atomicAdd(&s_cntX[x], 1u);
    }
    __syncthreads();
    if (tid == 0) {
        unsigned run = 0;
        for (int x = 0; x < GX; ++x) { tiedPrefX[x] = run; run += s_cntX[x]; }
        *nTiedG = (unsigned)n;
        sel[0] = T;
        sel[1] = R;
    }
    if (tid < n) tiedList[tid] = s_list[tid];
}

// K3: output. Zero-store FIRST (dependency-free, fill-rate issue), then compute
// keep and re-store the ~3% kept voxels. Normal stores (L2 path, like the
// 7.1 TB/s rocclr fill). Same-lane same-address stores retire in program order.
__global__ __launch_bounds__(256) void k_out(
    const float* __restrict__ occL,
    const float* __restrict__ matL,
    const float* __restrict__ mvp,
    const unsigned* __restrict__ depthBits,
    const unsigned* __restrict__ sel,
    const unsigned* __restrict__ tiedList,
    const unsigned* __restrict__ tiedPrefX,
    const unsigned* __restrict__ nTiedPtr,
    float* __restrict__ out)
{
    int i = blockIdx.x * 256 + threadIdx.x;
    if (i >= NVOX) return;
    int x = i / GRP;
    int g = i - x * GRP;

    f4* op = reinterpret_cast<f4*>(out) + (size_t)i * 2;
    op[0] = (f4)(0.0f);
    op[1] = (f4)(0.0f);
    asm volatile("" ::: "memory");           // keep the zero stores (no DCE)

    float occ;
    bool valid = voxel_valid(x, g, occL, mvp, &occ);
    bool keep = false;
    if (valid) {
        unsigned T  = sel[0];
        unsigned db = depthBits[g];
        if (db < T) {
            keep = true;
        } else if (db == T) {
            unsigned R = sel[1];
            unsigned rank = tiedPrefX[x];
            int n = (int)*nTiedPtr;
            for (int s = 0; s < n; ++s) {
                unsigned gs = tiedList[s];
                if (gs >= (unsigned)g) break;
                float o2;
                if (voxel_valid(x, (int)gs, occL, mvp, &o2)) ++rank;
            }
            keep = rank < R;
        }
    }

    if (keep) {
        const f4* mp = reinterpret_cast<const f4*>(matL) + (size_t)i * 2;
        f4 a = __builtin_nontemporal_load(mp);
        f4 b = __builtin_nontemporal_load(mp + 1);
        float mx = fmaxf(fmaxf(fmaxf(a[0], a[1]), fmaxf(a[2], a[3])),
                         fmaxf(fmaxf(b[0], b[1]), fmaxf(b[2], b[3])));
        float e0 = expf(a[0] - mx), e1 = expf(a[1] - mx), e2 = expf(a[2] - mx), e3 = expf(a[3] - mx);
        float e4 = expf(b[0] - mx), e5 = expf(b[1] - mx), e6 = expf(b[2] - mx), e7 = expf(b[3] - mx);
        float s = ((e0 + e1) + (e2 + e3)) + ((e4 + e5) + (e6 + e7));
        float inv = occ / s;
        f4 o0, o1;
        o0[0] = e0 * inv; o0[1] = e1 * inv; o0[2] = e2 * inv; o0[3] = e3 * inv;
        o1[0] = e4 * inv; o1[1] = e5 * inv; o1[2] = e6 * inv; o1[3] = e7 * inv;
        op[0] = o0;
        op[1] = o1;
    }
}

extern "C" void kernel_launch(void* const* d_in, const int* in_sizes, int n_in,
                              void* d_out, int out_size, void* d_ws, size_t ws_size,
                              hipStream_t stream)
{
    const float* occL = (const float*)d_in[0];
    const float* matL = (const float*)d_in[1];
    const float* view = (const float*)d_in[2];
    const float* proj = (const float*)d_in[3];
    const int*   mb   = (const int*)d_in[4];

    char* ws = (char*)d_ws;
    float*          mvp      = (float*)(ws + WS_MVP);
    unsigned char*  g16      = (unsigned char*)(ws + WS_G16);
    unsigned*       depthB   = (unsigned*)(ws + WS_DEPTH);
    unsigned*       sel      = (unsigned*)(ws + WS_SEL);
    unsigned*       tiedList = (unsigned*)(ws + WS_TLIST);
    unsigned*       tiedPref = (unsigned*)(ws + WS_TPREF);
    unsigned*       nTied    = (unsigned*)(ws + WS_NTIED);

    k_prep_count<<<NXC * GBLK, 256, 0, stream>>>(view, proj, occL, mvp, g16, depthB);
    k_select<<<1, K2T, 0, stream>>>(view, proj, occL, g16, mb,
                                    sel, tiedList, tiedPref, nTied);
    k_out<<<NVOX / 256, 256, 0, stream>>>(occL, matL, mvp, depthB, sel,
                                          tiedList, tiedPref, nTied, (float*)d_out);
}